// Round 1
// baseline (1586.321 us; speedup 1.0000x reference)
//
#include <hip/hip_runtime.h>

#define N_NODES 200000
#define N_DIM   64
#define N_EDGES 6400000

// ---------------- CSR build ----------------

__global__ __launch_bounds__(256) void k_count(const int* __restrict__ rows,
                                               int* __restrict__ deg) {
    int e = blockIdx.x * 256 + threadIdx.x;           // grid exact: E % 256 == 0
    atomicAdd(&deg[rows[e]], 1);
}

// block-level partial sums over 1024-element chunks
__global__ __launch_bounds__(256) void k_scan1(const int* __restrict__ deg,
                                               int* __restrict__ partial) {
    __shared__ int sm[256];
    int t = threadIdx.x;
    int base = blockIdx.x * 1024 + t * 4;
    int s = 0;
#pragma unroll
    for (int i = 0; i < 4; ++i) {
        int idx = base + i;
        if (idx < N_NODES) s += deg[idx];
    }
    sm[t] = s;
    __syncthreads();
    for (int off = 128; off > 0; off >>= 1) {
        if (t < off) sm[t] += sm[t + off];
        __syncthreads();
    }
    if (t == 0) partial[blockIdx.x] = sm[0];
}

// exclusive-scan the ~196 block sums; write grand total to offsets[N]
__global__ __launch_bounds__(256) void k_scan2(int* __restrict__ partial, int nb,
                                               int* __restrict__ offsets) {
    __shared__ int sm[256];
    int t = threadIdx.x;
    sm[t] = (t < nb) ? partial[t] : 0;
    __syncthreads();
    if (t == 0) {
        int run = 0;
        for (int i = 0; i < nb; ++i) { int v = sm[i]; sm[i] = run; run += v; }
        offsets[N_NODES] = run;
    }
    __syncthreads();
    if (t < nb) partial[t] = sm[t];
}

// final scan: offsets[] = global exclusive prefix of deg[]; also init cursor[]
__global__ __launch_bounds__(256) void k_scan3(const int* __restrict__ deg,
                                               const int* __restrict__ partial,
                                               int* __restrict__ offsets,
                                               int* __restrict__ cursor) {
    __shared__ int sm[256];
    int t = threadIdx.x;
    int base = blockIdx.x * 1024 + t * 4;
    int v[4];
#pragma unroll
    for (int i = 0; i < 4; ++i) {
        int idx = base + i;
        v[i] = (idx < N_NODES) ? deg[idx] : 0;
    }
    int p1 = v[0], p2 = v[0] + v[1], p3 = p2 + v[2];
    sm[t] = p3 + v[3];
    __syncthreads();
    // Hillis-Steele inclusive scan over thread sums
    for (int off = 1; off < 256; off <<= 1) {
        int x = (t >= off) ? sm[t - off] : 0;
        __syncthreads();
        sm[t] += x;
        __syncthreads();
    }
    int excl = (t == 0) ? 0 : sm[t - 1];
    int rowbase = partial[blockIdx.x] + excl;
    int pre[4] = {0, p1, p2, p3};
#pragma unroll
    for (int i = 0; i < 4; ++i) {
        int idx = base + i;
        if (idx < N_NODES) {
            int o = rowbase + pre[i];
            offsets[idx] = o;
            cursor[idx]  = o;
        }
    }
}

__global__ __launch_bounds__(256) void k_scatter(const int* __restrict__ rows,
                                                 const int* __restrict__ cols,
                                                 const float* __restrict__ vals,
                                                 int* __restrict__ cursor,
                                                 int2* __restrict__ csr) {
    int e = blockIdx.x * 256 + threadIdx.x;           // grid exact
    int r = rows[e];
    int pos = atomicAdd(&cursor[r], 1);
    csr[pos] = make_int2(cols[e], __float_as_int(vals[e]));
}

// ---------------- SpMM (CSR, 16 lanes per row, float4 per lane) ----------------
// MODE 0: y = A@x; accOut = accIn(emb) + y
// MODE 1: y = A@x; accOut += y
// MODE 2: h = A@x (not stored); accOut = (accOut + h) * 0.25
template <int MODE>
__global__ __launch_bounds__(256) void spmm_csr(const int* __restrict__ offsets,
                                                const int2* __restrict__ csr,
                                                const float* __restrict__ x,
                                                float* __restrict__ y,
                                                const float* __restrict__ accIn,
                                                float* __restrict__ accOut) {
    int tid  = threadIdx.x;
    int r    = blockIdx.x * 16 + (tid >> 4);          // grid exact: N % 16 == 0
    int lane = tid & 15;

    int start = offsets[r];
    int end   = offsets[r + 1];

    float4 acc = make_float4(0.f, 0.f, 0.f, 0.f);
#pragma unroll 4
    for (int j = start; j < end; ++j) {
        int2  cv = csr[j];
        float v  = __int_as_float(cv.y);
        const float4 xr = *reinterpret_cast<const float4*>(x + (cv.x << 6) + (lane << 2));
        acc.x = fmaf(v, xr.x, acc.x);
        acc.y = fmaf(v, xr.y, acc.y);
        acc.z = fmaf(v, xr.z, acc.z);
        acc.w = fmaf(v, xr.w, acc.w);
    }

    int o = (r << 6) + (lane << 2);
    if (MODE == 0) {
        float4 e = *reinterpret_cast<const float4*>(accIn + o);
        *reinterpret_cast<float4*>(y + o) = acc;
        float4 a = make_float4(e.x + acc.x, e.y + acc.y, e.z + acc.z, e.w + acc.w);
        *reinterpret_cast<float4*>(accOut + o) = a;
    } else if (MODE == 1) {
        float4 a = *reinterpret_cast<const float4*>(accOut + o);
        *reinterpret_cast<float4*>(y + o) = acc;
        float4 s = make_float4(a.x + acc.x, a.y + acc.y, a.z + acc.z, a.w + acc.w);
        *reinterpret_cast<float4*>(accOut + o) = s;
    } else {
        float4 a = *reinterpret_cast<const float4*>(accOut + o);
        float4 s = make_float4((a.x + acc.x) * 0.25f, (a.y + acc.y) * 0.25f,
                               (a.z + acc.z) * 0.25f, (a.w + acc.w) * 0.25f);
        *reinterpret_cast<float4*>(accOut + o) = s;
    }
}

// ---------------- fallback: edge-parallel atomic SpMM (small ws) ----------------

__global__ __launch_bounds__(256) void spmm_atomic(const int* __restrict__ rows,
                                                   const int* __restrict__ cols,
                                                   const float* __restrict__ vals,
                                                   const float* __restrict__ x,
                                                   float* __restrict__ y) {
    int gid  = blockIdx.x * 256 + threadIdx.x;        // covers E*16
    int e    = gid >> 4;
    int lane = gid & 15;
    float v = vals[e];
    const float4 xr = *reinterpret_cast<const float4*>(x + (cols[e] << 6) + (lane << 2));
    float* yp = y + (rows[e] << 6) + (lane << 2);
    atomicAdd(yp + 0, v * xr.x);
    atomicAdd(yp + 1, v * xr.y);
    atomicAdd(yp + 2, v * xr.z);
    atomicAdd(yp + 3, v * xr.w);
}

template <int MODE>
__global__ __launch_bounds__(256) void k_accum(const float* __restrict__ emb,
                                               const float* __restrict__ y,
                                               float* __restrict__ out) {
    int i = (blockIdx.x * 256 + threadIdx.x) << 2;    // float4 index space, grid exact
    float4 h = *reinterpret_cast<const float4*>(y + i);
    if (MODE == 0) {
        float4 e = *reinterpret_cast<const float4*>(emb + i);
        *reinterpret_cast<float4*>(out + i) =
            make_float4(e.x + h.x, e.y + h.y, e.z + h.z, e.w + h.w);
    } else if (MODE == 1) {
        float4 a = *reinterpret_cast<const float4*>(out + i);
        *reinterpret_cast<float4*>(out + i) =
            make_float4(a.x + h.x, a.y + h.y, a.z + h.z, a.w + h.w);
    } else {
        float4 a = *reinterpret_cast<const float4*>(out + i);
        *reinterpret_cast<float4*>(out + i) =
            make_float4((a.x + h.x) * 0.25f, (a.y + h.y) * 0.25f,
                        (a.z + h.z) * 0.25f, (a.w + h.w) * 0.25f);
    }
}

// ---------------- launch ----------------

extern "C" void kernel_launch(void* const* d_in, const int* in_sizes, int n_in,
                              void* d_out, int out_size, void* d_ws, size_t ws_size,
                              hipStream_t stream) {
    const float* emb  = (const float*)d_in[0];
    const float* vals = (const float*)d_in[1];
    const int*   rows = (const int*)d_in[2];
    const int*   cols = (const int*)d_in[3];
    float*       out  = (float*)d_out;
    char*        ws   = (char*)d_ws;

    const size_t NB = (size_t)N_NODES * N_DIM * sizeof(float);   // 51,200,000
    const size_t CSR_BYTES = (size_t)N_EDGES * 8;                // 51,200,000

    // CSR-path workspace layout
    const size_t OFF_DEG     = 0;
    const size_t OFF_OFFSETS = 1u << 20;
    const size_t OFF_CURSOR  = 2u << 20;
    const size_t OFF_PARTIAL = 3u << 20;
    const size_t OFF_CSR     = 4u << 20;
    const size_t OFF_BUFA    = OFF_CSR + CSR_BYTES;
    const size_t OFF_BUFB    = OFF_BUFA + NB;
    const size_t CSR_NEED    = OFF_BUFB + NB;                    // ~151 MiB

    const int NBLK_SCAN = (N_NODES + 1023) / 1024;               // 196
    const int EB = N_EDGES / 256;                                // 25000
    const int RB = N_NODES / 16;                                 // 12500

    if (ws_size >= CSR_NEED) {
        int*   deg     = (int*)(ws + OFF_DEG);
        int*   offsets = (int*)(ws + OFF_OFFSETS);
        int*   cursor  = (int*)(ws + OFF_CURSOR);
        int*   partial = (int*)(ws + OFF_PARTIAL);
        int2*  csr     = (int2*)(ws + OFF_CSR);
        float* bufA    = (float*)(ws + OFF_BUFA);
        float* bufB    = (float*)(ws + OFF_BUFB);

        hipMemsetAsync(deg, 0, N_NODES * sizeof(int), stream);
        k_count<<<EB, 256, 0, stream>>>(rows, deg);
        k_scan1<<<NBLK_SCAN, 256, 0, stream>>>(deg, partial);
        k_scan2<<<1, 256, 0, stream>>>(partial, NBLK_SCAN, offsets);
        k_scan3<<<NBLK_SCAN, 256, 0, stream>>>(deg, partial, offsets, cursor);
        k_scatter<<<EB, 256, 0, stream>>>(rows, cols, vals, cursor, csr);

        spmm_csr<0><<<RB, 256, 0, stream>>>(offsets, csr, emb,  bufA, emb, out);
        spmm_csr<1><<<RB, 256, 0, stream>>>(offsets, csr, bufA, bufB, nullptr, out);
        spmm_csr<2><<<RB, 256, 0, stream>>>(offsets, csr, bufB, bufA, nullptr, out);
    } else {
        // fallback: edge-parallel atomics, needs only 2 dense buffers (~98 MiB)
        float* bufA = (float*)ws;
        float* bufB = (float*)(ws + NB);
        const int AB = (N_EDGES * 16) / 256;                     // 400000
        const int VB = (N_NODES * N_DIM / 4) / 256;              // 12500

        hipMemsetAsync(bufA, 0, NB, stream);
        spmm_atomic<<<AB, 256, 0, stream>>>(rows, cols, vals, emb, bufA);
        k_accum<0><<<VB, 256, 0, stream>>>(emb, bufA, out);

        hipMemsetAsync(bufB, 0, NB, stream);
        spmm_atomic<<<AB, 256, 0, stream>>>(rows, cols, vals, bufA, bufB);
        k_accum<1><<<VB, 256, 0, stream>>>(nullptr, bufB, out);

        hipMemsetAsync(bufA, 0, NB, stream);
        spmm_atomic<<<AB, 256, 0, stream>>>(rows, cols, vals, bufB, bufA);
        k_accum<2><<<VB, 256, 0, stream>>>(nullptr, bufA, out);
    }
}